// Round 2
// baseline (410.538 us; speedup 1.0000x reference)
//
#include <hip/hip_runtime.h>
#include <hip/hip_bf16.h>

#define H   768
#define H4  3072
#define S   256
#define BB  2
#define M   (BB * S)          // 512 rows of (b,t)
#define LRC 0.01f

typedef __attribute__((ext_vector_type(8))) short bf16x8;
typedef __attribute__((ext_vector_type(4))) float f32x4;

__device__ inline bf16x8 cvt8(const float* __restrict__ p) {
    bf16x8 r;
#pragma unroll
    for (int i = 0; i < 8; ++i) {
        __hip_bfloat16 h = __float2bfloat16(p[i]);
        r[i] = *reinterpret_cast<const short*>(&h);
    }
    return r;
}

// ---------------- K1: sequential fast-weight recurrence (pure f32) --------
// One wave per (b,h): owns row W[h,:] in registers (12 f32/lane), runs all
// S steps: pred_t[h] = W.x_t + bias; W -= LR*diff*x_t; bias -= LR*diff.
__global__ __launch_bounds__(256) void k_recur(
    const float* __restrict__ x,
    const float* __restrict__ W0,
    const float* __restrict__ b0,
    float* __restrict__ pred_f,
    __hip_bfloat16* __restrict__ pred_h)
{
    const int wave = blockIdx.x * 4 + (threadIdx.x >> 6);
    const int lane = threadIdx.x & 63;
    const int b = wave / H;
    const int h = wave % H;
    const float* xb = x + b * S * H;

    float wrow[12];
#pragma unroll
    for (int j = 0; j < 12; ++j)
        wrow[j] = W0[h * H + lane + 64 * j];
    float bias = b0[h];

    for (int t = 0; t < S; ++t) {
        float xv[12];
        float part = 0.f;
#pragma unroll
        for (int j = 0; j < 12; ++j) {
            xv[j] = xb[t * H + lane + 64 * j];
            part += wrow[j] * xv[j];
        }
#pragma unroll
        for (int off = 32; off >= 1; off >>= 1)
            part += __shfl_xor(part, off, 64);
        const float pred = part + bias;
        if (lane == 0) {
            pred_f[(b * S + t) * H + h] = pred;
            pred_h[(b * S + t) * H + h] = __float2bfloat16(pred);
        }
        if (t + 1 < S) {
            const float xn = xb[(t + 1) * H + h];
            const float d = LRC * (pred - xn);
#pragma unroll
            for (int j = 0; j < 12; ++j)
                wrow[j] -= d * xv[j];
            bias -= d;
        }
    }
}

// ---------------- K2: gate/up GEMMs + sigmoid*up fusion ----------------
// hidden[m,n] = sigmoid(pred.gate_w[n,:]+gate_b[n]) * (pred.up_w[n,:]+up_b[n])
// A from bf16-staged pred; B rows (f32 weights, [n][k] layout) cvt'd inline.
__global__ __launch_bounds__(256) void k_gateup(
    const __hip_bfloat16* __restrict__ predh,
    const float* __restrict__ gw,
    const float* __restrict__ gb,
    const float* __restrict__ uw,
    const float* __restrict__ ub,
    __hip_bfloat16* __restrict__ hid)
{
    const int wid = threadIdx.x >> 6, lane = threadIdx.x & 63;
    const int m0 = blockIdx.y * 16;
    const int n0 = blockIdx.x * 64 + wid * 16;
    const int r16 = lane & 15, quad = lane >> 4;

    f32x4 accg = {0.f, 0.f, 0.f, 0.f};
    f32x4 accu = {0.f, 0.f, 0.f, 0.f};
    const short* A  = (const short*)predh + (m0 + r16) * H;
    const float* Bg = gw + (n0 + r16) * H;
    const float* Bu = uw + (n0 + r16) * H;

    for (int k0 = 0; k0 < H; k0 += 32) {
        const int k = k0 + quad * 8;
        bf16x8 af = *(const bf16x8*)(A + k);
        bf16x8 bg = cvt8(Bg + k);
        bf16x8 bu = cvt8(Bu + k);
        accg = __builtin_amdgcn_mfma_f32_16x16x32_bf16(af, bg, accg, 0, 0, 0);
        accu = __builtin_amdgcn_mfma_f32_16x16x32_bf16(af, bu, accu, 0, 0, 0);
    }
    // C/D layout: col(n) = lane&15, row(m) = quad*4 + r   [m89/m91]
    const int ocol = n0 + r16;
    const float gbv = gb[ocol];
    const float ubv = ub[ocol];
#pragma unroll
    for (int r = 0; r < 4; ++r) {
        const int orow = m0 + quad * 4 + r;
        const float g = accg[r] + gbv;
        const float u = accu[r] + ubv;
        const float sg = 1.f / (1.f + __expf(-g));
        hid[orow * H4 + ocol] = __float2bfloat16(sg * u);
    }
}

// ---------------- K3: down GEMM + bias + pred residual ----------------
__global__ __launch_bounds__(256) void k_down(
    const __hip_bfloat16* __restrict__ hid,
    const float* __restrict__ dw,
    const float* __restrict__ db,
    const float* __restrict__ predf,
    float* __restrict__ dout)
{
    const int wid = threadIdx.x >> 6, lane = threadIdx.x & 63;
    const int m0 = blockIdx.y * 16;
    const int n0 = blockIdx.x * 64 + wid * 16;
    const int r16 = lane & 15, quad = lane >> 4;

    f32x4 acc = {0.f, 0.f, 0.f, 0.f};
    const short* A  = (const short*)hid + (m0 + r16) * H4;
    const float* Bd = dw + (n0 + r16) * H4;

    for (int k0 = 0; k0 < H4; k0 += 32) {
        const int k = k0 + quad * 8;
        bf16x8 af = *(const bf16x8*)(A + k);
        bf16x8 bd = cvt8(Bd + k);
        acc = __builtin_amdgcn_mfma_f32_16x16x32_bf16(af, bd, acc, 0, 0, 0);
    }
    const int ocol = n0 + r16;
    const float dbv = db[ocol];
#pragma unroll
    for (int r = 0; r < 4; ++r) {
        const int orow = m0 + quad * 4 + r;
        dout[orow * H + ocol] = acc[r] + dbv + predf[orow * H + ocol];
    }
}

// ---------------- K4: row-wise LayerNorm -> f32 out ----------------
__global__ __launch_bounds__(256) void k_ln(
    const float* __restrict__ dout,
    const float* __restrict__ nw,
    const float* __restrict__ nb,
    float* __restrict__ out)
{
    const int m = blockIdx.x;
    const int tid = threadIdx.x;
    const float* rowp = dout + m * H;

    float v[3];
    float s = 0.f, s2 = 0.f;
#pragma unroll
    for (int j = 0; j < 3; ++j) {
        v[j] = rowp[tid + 256 * j];
        s += v[j];
        s2 += v[j] * v[j];
    }
#pragma unroll
    for (int off = 32; off >= 1; off >>= 1) {
        s  += __shfl_xor(s, off, 64);
        s2 += __shfl_xor(s2, off, 64);
    }
    __shared__ float rs[4], rs2[4];
    const int wid = tid >> 6, lane = tid & 63;
    if (lane == 0) { rs[wid] = s; rs2[wid] = s2; }
    __syncthreads();
    s  = rs[0] + rs[1] + rs[2] + rs[3];
    s2 = rs2[0] + rs2[1] + rs2[2] + rs2[3];
    const float mu  = s / (float)H;
    const float var = s2 / (float)H - mu * mu;
    const float inv = rsqrtf(var + 1e-5f);
#pragma unroll
    for (int j = 0; j < 3; ++j) {
        const int hh = tid + 256 * j;
        const float y = (v[j] - mu) * inv * nw[hh] + nb[hh];
        out[m * H + hh] = y;
    }
}

// ---------------- launch ----------------
extern "C" void kernel_launch(void* const* d_in, const int* in_sizes, int n_in,
                              void* d_out, int out_size, void* d_ws, size_t ws_size,
                              hipStream_t stream)
{
    const float* x   = (const float*)d_in[0];
    const float* W0  = (const float*)d_in[1];
    const float* b0  = (const float*)d_in[2];
    const float* gw  = (const float*)d_in[3];
    const float* gb  = (const float*)d_in[4];
    const float* uw  = (const float*)d_in[5];
    const float* ub  = (const float*)d_in[6];
    const float* dw  = (const float*)d_in[7];
    const float* db  = (const float*)d_in[8];
    const float* nw  = (const float*)d_in[9];
    const float* nb  = (const float*)d_in[10];

    char* ws = (char*)d_ws;
    float*          pred_f = (float*)(ws);                       // 512*768*4  = 1572864 B
    __hip_bfloat16* pred_h = (__hip_bfloat16*)(ws + 1572864);    // 512*768*2  =  786432 B
    __hip_bfloat16* hid    = (__hip_bfloat16*)(ws + 2359296);    // 512*3072*2 = 3145728 B
    float*          dout_f = (float*)(ws + 5505024);             // 512*768*4  = 1572864 B

    k_recur<<<dim3((BB * H) / 4), 256, 0, stream>>>(x, W0, b0, pred_f, pred_h);
    k_gateup<<<dim3(H4 / 64, M / 16), 256, 0, stream>>>(pred_h, gw, gb, uw, ub, hid);
    k_down<<<dim3(H / 64, M / 16), 256, 0, stream>>>(hid, dw, db, pred_f, dout_f);
    k_ln<<<dim3(M), 256, 0, stream>>>(dout_f, nw, nb, (float*)d_out);
}

// Round 3
// 401.489 us; speedup vs baseline: 1.0225x; 1.0225x over previous
//
#include <hip/hip_runtime.h>
#include <hip/hip_bf16.h>

#define H   768
#define H4  3072
#define S   256
#define BB  2
#define M   (BB * S)          // 512 rows of (b,t)
#define LRC 0.01f
#define C   64                // recurrence chunk size
#define NC  (S / C)           // 4 chunks

typedef __attribute__((ext_vector_type(8))) short bf16x8;
typedef __attribute__((ext_vector_type(4))) float f32x4;

// ---------------- K0: Gram matrices G1[b][c][s][t] = x_s.x_t + 1 ----------
// One wg per (b, c, quarter-of-t). 32 wgs.
__global__ __launch_bounds__(256) void k_gram(
    const float* __restrict__ x, float* __restrict__ g1)
{
    const int id = blockIdx.x;
    const int tq = id & 3, c = (id >> 2) & 3, b = id >> 4;
    const int tl = threadIdx.x >> 4;     // 0..15
    const int sl = threadIdx.x & 15;     // 0..15
    const int t = tq * 16 + tl;
    const float* xb = x + b * S * H;
    const float* xt = xb + (c * C + t) * H;
    float acc[4] = {0.f, 0.f, 0.f, 0.f};
    for (int k = 0; k < H; k += 4) {
        const float4 xv = *(const float4*)(xt + k);
#pragma unroll
        for (int j = 0; j < 4; ++j) {
            const float4 sv = *(const float4*)(xb + (c * C + sl + 16 * j) * H + k);
            acc[j] += xv.x * sv.x + xv.y * sv.y + xv.z * sv.z + xv.w * sv.w;
        }
    }
    float* gout = g1 + (b * NC + c) * C * C;
#pragma unroll
    for (int j = 0; j < 4; ++j)
        gout[(sl + 16 * j) * C + t] = acc[j] + 1.f;
}

// ---------------- K0b: f32 -> bf16 weight staging ----------------
__global__ __launch_bounds__(256) void k_cvt(
    const float* __restrict__ s, __hip_bfloat16* __restrict__ d, int n)
{
    const int i = (blockIdx.x * 256 + threadIdx.x) * 4;
    if (i + 3 < n) {
        const float4 v = *(const float4*)(s + i);
        d[i]     = __float2bfloat16(v.x);
        d[i + 1] = __float2bfloat16(v.y);
        d[i + 2] = __float2bfloat16(v.z);
        d[i + 3] = __float2bfloat16(v.w);
    }
}

// ---------------- K1: chunked fast-weight recurrence (pure f32) ----------
// Wave w of wg g owns row (b,h) = g*4+w. Lane l owns W[h][l*12 .. l*12+12).
// Per chunk: base matvec (parallel over t) -> serial scan via running
// per-lane correction (lane t owns corr_t) -> rank-C W update.
__global__ __launch_bounds__(256) void k_recur2(
    const float* __restrict__ x,
    const float* __restrict__ W0,
    const float* __restrict__ b0,
    const float* __restrict__ g1,
    float* __restrict__ pred_f,
    __hip_bfloat16* __restrict__ pred_h)
{
    __shared__ float Gp[C * 65];         // +1 pad: conflict-free scan reads
    const int tid = threadIdx.x;
    const int w = tid >> 6, lane = tid & 63;
    const int row = blockIdx.x * 4 + w;
    const int b = row / H, h = row % H;
    const float* xb = x + b * S * H;

    float wr[12];
    {
        const float* ws0 = W0 + h * H + lane * 12;
        *(float4*)(wr)     = *(const float4*)(ws0);
        *(float4*)(wr + 4) = *(const float4*)(ws0 + 4);
        *(float4*)(wr + 8) = *(const float4*)(ws0 + 8);
    }
    float bias = b0[h];

    for (int c = 0; c < NC; ++c) {
        const int t0 = c * C;
        __syncthreads();                 // prev chunk's Gp reads done
        const float* gsrc = g1 + (b * NC + c) * C * C;
        for (int i = tid; i < C * C; i += 256)
            Gp[(i >> 6) * 65 + (i & 63)] = gsrc[i];
        __syncthreads();

        // ---- base phase: lane t ends up holding base_t = W_c.x_t + b_c
        float base_r = 0.f;
#pragma unroll 2
        for (int t = 0; t < C; ++t) {
            const float* xt = xb + (t0 + t) * H + lane * 12;
            const float4 a  = *(const float4*)(xt);
            const float4 bq = *(const float4*)(xt + 4);
            const float4 cq = *(const float4*)(xt + 8);
            float p = wr[0]*a.x + wr[1]*a.y + wr[2]*a.z + wr[3]*a.w;
            p += wr[4]*bq.x + wr[5]*bq.y + wr[6]*bq.z + wr[7]*bq.w;
            p += wr[8]*cq.x + wr[9]*cq.y + wr[10]*cq.z + wr[11]*cq.w;
#pragma unroll
            for (int off = 32; off >= 1; off >>= 1)
                p += __shfl_xor(p, off, 64);
            if (lane == t) base_r = p + bias;
        }

        // ---- scan phase: lane s holds diff_s, pred_s
        const int tg = t0 + lane;
        const int tn = (tg + 1 < S) ? tg + 1 : S - 1;
        const float xn = xb[tn * H + h];
        float corr = 0.f;
        float pred = base_r;
        float diff = pred - xn;          // valid for lane 0
        for (int s = 0; s < C - 1; ++s) {
            const float dbc = __shfl(diff, s, 64);
            corr += dbc * Gp[s * 65 + lane];
            const float pl = base_r - LRC * corr;
            const float dl = pl - xn;
            if (lane == s + 1) { pred = pl; diff = dl; }
        }
        if (tg == S - 1) diff = 0.f;     // lr=0 at last token

        pred_f[(b * S + tg) * H + h] = pred;
        pred_h[(b * S + tg) * H + h] = __float2bfloat16(pred);

        // ---- update phase: W -= lr * sum_s diff_s x_s^T ; b -= lr * sum diff
        float sd = 0.f;
        for (int s = 0; s < C; ++s) {
            const float dbc = __shfl(diff, s, 64);
            sd += dbc;
            const float f = LRC * dbc;
            const float* xs = xb + (t0 + s) * H + lane * 12;
            const float4 a  = *(const float4*)(xs);
            const float4 bq = *(const float4*)(xs + 4);
            const float4 cq = *(const float4*)(xs + 8);
            wr[0] -= f*a.x;  wr[1] -= f*a.y;  wr[2]  -= f*a.z;  wr[3]  -= f*a.w;
            wr[4] -= f*bq.x; wr[5] -= f*bq.y; wr[6]  -= f*bq.z; wr[7]  -= f*bq.w;
            wr[8] -= f*cq.x; wr[9] -= f*cq.y; wr[10] -= f*cq.z; wr[11] -= f*cq.w;
        }
        bias -= LRC * sd;
    }
}

// ---------------- B-fragment loaders ----------------
__device__ inline bf16x8 ldb16(const void* p, long off) {
    return *(const bf16x8*)((const short*)p + off);
}
__device__ inline bf16x8 ldb32(const void* p, long off) {
    const float* f = (const float*)p + off;
    const float4 a = *(const float4*)f;
    const float4 b = *(const float4*)(f + 4);
    bf16x8 r;
    __hip_bfloat16 t;
    t = __float2bfloat16(a.x); r[0] = *(short*)&t;
    t = __float2bfloat16(a.y); r[1] = *(short*)&t;
    t = __float2bfloat16(a.z); r[2] = *(short*)&t;
    t = __float2bfloat16(a.w); r[3] = *(short*)&t;
    t = __float2bfloat16(b.x); r[4] = *(short*)&t;
    t = __float2bfloat16(b.y); r[5] = *(short*)&t;
    t = __float2bfloat16(b.z); r[6] = *(short*)&t;
    t = __float2bfloat16(b.w); r[7] = *(short*)&t;
    return r;
}

// ---------------- K2: gate/up GEMMs + sigmoid*up, 64m x 16n per wave ------
template<bool WB>
__global__ __launch_bounds__(256) void k_gateup2(
    const __hip_bfloat16* __restrict__ predh,
    const void* __restrict__ gw, const float* __restrict__ gb,
    const void* __restrict__ uw, const float* __restrict__ ub,
    __hip_bfloat16* __restrict__ hid)
{
    const int wid = threadIdx.x >> 6, lane = threadIdx.x & 63;
    const int r16 = lane & 15, quad = lane >> 4;
    const int m0 = blockIdx.y * 64;
    const int n0 = blockIdx.x * 64 + wid * 16;

    f32x4 ag[4], au[4];
#pragma unroll
    for (int i = 0; i < 4; ++i) { ag[i] = (f32x4){0,0,0,0}; au[i] = (f32x4){0,0,0,0}; }
    const short* A = (const short*)predh;
    const long brow = (long)(n0 + r16) * H;

    for (int k0 = 0; k0 < H; k0 += 32) {
        const int k = k0 + quad * 8;
        const bf16x8 bg = WB ? ldb16(gw, brow + k) : ldb32(gw, brow + k);
        const bf16x8 bu = WB ? ldb16(uw, brow + k) : ldb32(uw, brow + k);
#pragma unroll
        for (int i = 0; i < 4; ++i) {
            const bf16x8 af = *(const bf16x8*)(A + (m0 + i * 16 + r16) * H + k);
            ag[i] = __builtin_amdgcn_mfma_f32_16x16x32_bf16(af, bg, ag[i], 0, 0, 0);
            au[i] = __builtin_amdgcn_mfma_f32_16x16x32_bf16(af, bu, au[i], 0, 0, 0);
        }
    }
    const int ocol = n0 + r16;
    const float gbv = gb[ocol], ubv = ub[ocol];
#pragma unroll
    for (int i = 0; i < 4; ++i)
#pragma unroll
        for (int r = 0; r < 4; ++r) {
            const int orow = m0 + i * 16 + quad * 4 + r;
            const float g = ag[i][r] + gbv;
            const float u = au[i][r] + ubv;
            const float sg = 1.f / (1.f + __expf(-g));
            hid[orow * H4 + ocol] = __float2bfloat16(sg * u);
        }
}

// ---------------- K3: down GEMM + bias + pred residual, 32m x 16n/wave ----
template<bool WB>
__global__ __launch_bounds__(256) void k_down2(
    const __hip_bfloat16* __restrict__ hid,
    const void* __restrict__ dw, const float* __restrict__ db,
    const float* __restrict__ predf, float* __restrict__ dout)
{
    const int wid = threadIdx.x >> 6, lane = threadIdx.x & 63;
    const int r16 = lane & 15, quad = lane >> 4;
    const int m0 = blockIdx.y * 32;
    const int n0 = blockIdx.x * 64 + wid * 16;

    f32x4 ac[2];
    ac[0] = (f32x4){0,0,0,0}; ac[1] = (f32x4){0,0,0,0};
    const short* A = (const short*)hid;
    const long brow = (long)(n0 + r16) * H4;

    for (int k0 = 0; k0 < H4; k0 += 32) {
        const int k = k0 + quad * 8;
        const bf16x8 bd = WB ? ldb16(dw, brow + k) : ldb32(dw, brow + k);
#pragma unroll
        for (int i = 0; i < 2; ++i) {
            const bf16x8 af = *(const bf16x8*)(A + (m0 + i * 16 + r16) * H4 + k);
            ac[i] = __builtin_amdgcn_mfma_f32_16x16x32_bf16(af, bd, ac[i], 0, 0, 0);
        }
    }
    const int ocol = n0 + r16;
    const float dbv = db[ocol];
#pragma unroll
    for (int i = 0; i < 2; ++i)
#pragma unroll
        for (int r = 0; r < 4; ++r) {
            const int orow = m0 + i * 16 + quad * 4 + r;
            dout[orow * H + ocol] = ac[i][r] + dbv + predf[orow * H + ocol];
        }
}

// ---------------- K4: row-wise LayerNorm -> f32 out ----------------
__global__ __launch_bounds__(256) void k_ln(
    const float* __restrict__ dout,
    const float* __restrict__ nw,
    const float* __restrict__ nb,
    float* __restrict__ out)
{
    const int m = blockIdx.x;
    const int tid = threadIdx.x;
    const float* rowp = dout + m * H;

    float v[3];
    float s = 0.f, s2 = 0.f;
#pragma unroll
    for (int j = 0; j < 3; ++j) {
        v[j] = rowp[tid + 256 * j];
        s += v[j];
        s2 += v[j] * v[j];
    }
#pragma unroll
    for (int off = 32; off >= 1; off >>= 1) {
        s  += __shfl_xor(s, off, 64);
        s2 += __shfl_xor(s2, off, 64);
    }
    __shared__ float rs[4], rs2[4];
    const int wid = tid >> 6, lane = tid & 63;
    if (lane == 0) { rs[wid] = s; rs2[wid] = s2; }
    __syncthreads();
    s  = rs[0] + rs[1] + rs[2] + rs[3];
    s2 = rs2[0] + rs2[1] + rs2[2] + rs2[3];
    const float mu  = s / (float)H;
    const float var = s2 / (float)H - mu * mu;
    const float inv = rsqrtf(var + 1e-5f);
#pragma unroll
    for (int j = 0; j < 3; ++j) {
        const int hh = tid + 256 * j;
        out[m * H + hh] = (v[j] - mu) * inv * nw[hh] + nb[hh];
    }
}

// ---------------- launch ----------------
extern "C" void kernel_launch(void* const* d_in, const int* in_sizes, int n_in,
                              void* d_out, int out_size, void* d_ws, size_t ws_size,
                              hipStream_t stream)
{
    const float* x   = (const float*)d_in[0];
    const float* W0  = (const float*)d_in[1];
    const float* b0  = (const float*)d_in[2];
    const float* gw  = (const float*)d_in[3];
    const float* gb  = (const float*)d_in[4];
    const float* uw  = (const float*)d_in[5];
    const float* ub  = (const float*)d_in[6];
    const float* dw  = (const float*)d_in[7];
    const float* db  = (const float*)d_in[8];
    const float* nw  = (const float*)d_in[9];
    const float* nb  = (const float*)d_in[10];

    char* ws = (char*)d_ws;
    float*          pred_f = (float*)(ws);                       // 1572864 B
    __hip_bfloat16* pred_h = (__hip_bfloat16*)(ws + 1572864);    //  786432 B
    __hip_bfloat16* hid    = (__hip_bfloat16*)(ws + 2359296);    // 3145728 B
    float*          dout_f = (float*)(ws + 5505024);             // 1572864 B
    // G1 aliases the dout region (consumed by k_recur2 before k_down2 writes)
    float*          g1     = (float*)(ws + 5505024);             //  131072 B

    const size_t WNEED = 7077888ULL + 3ULL * 4718592ULL;         // + bf16 weights
    const bool wb = ws_size >= WNEED;
    __hip_bfloat16* gw2 = (__hip_bfloat16*)(ws + 7077888);
    __hip_bfloat16* uw2 = (__hip_bfloat16*)(ws + 7077888 + 4718592);
    __hip_bfloat16* dw2 = (__hip_bfloat16*)(ws + 7077888 + 2 * 4718592);
    const int WN = H * H4;   // 2359296 elements per weight matrix

    k_gram<<<dim3(BB * NC * 4), 256, 0, stream>>>(x, g1);
    if (wb) {
        k_cvt<<<dim3(WN / 1024), 256, 0, stream>>>(gw, gw2, WN);
        k_cvt<<<dim3(WN / 1024), 256, 0, stream>>>(uw, uw2, WN);
        k_cvt<<<dim3(WN / 1024), 256, 0, stream>>>(dw, dw2, WN);
    }
    k_recur2<<<dim3((BB * H) / 4), 256, 0, stream>>>(x, W0, b0, g1, pred_f, pred_h);
    if (wb) {
        k_gateup2<true><<<dim3(H4 / 64, M / 64), 256, 0, stream>>>(pred_h, gw2, gb, uw2, ub, hid);
        k_down2<true><<<dim3(H / 64, M / 32), 256, 0, stream>>>(hid, dw2, db, pred_f, dout_f);
    } else {
        k_gateup2<false><<<dim3(H4 / 64, M / 64), 256, 0, stream>>>(pred_h, gw, gb, uw, ub, hid);
        k_down2<false><<<dim3(H / 64, M / 32), 256, 0, stream>>>(hid, dw, db, pred_f, dout_f);
    }
    k_ln<<<dim3(M), 256, 0, stream>>>(dout_f, nw, nb, (float*)d_out);
}

// Round 4
// 267.793 us; speedup vs baseline: 1.5330x; 1.4993x over previous
//
#include <hip/hip_runtime.h>
#include <hip/hip_bf16.h>

#define H   768
#define H4  3072
#define S   256
#define BB  2
#define M   (BB * S)          // 512 rows of (b,t)
#define LRC 0.01f
#define C   64                // chunk size
#define NC  (S / C)           // 4 chunks

typedef __attribute__((ext_vector_type(8))) short bf16x8;
typedef __attribute__((ext_vector_type(4))) float f32x4;

__device__ inline short bfbits(float f) {
    __hip_bfloat16 h = __float2bfloat16(f);
    return *reinterpret_cast<short*>(&h);
}

// ---------------- K_split: f32 -> (hi, lo) bf16 pair ----------------
__global__ __launch_bounds__(256) void k_split(
    const float* __restrict__ s, short* __restrict__ hi,
    short* __restrict__ lo, int n)
{
    const int i = (blockIdx.x * 256 + threadIdx.x) * 4;
    if (i + 3 >= n + 1 && i >= n) return;
    const float4 v = *(const float4*)(s + i);
    short h4[4], l4[4];
    const float vf[4] = {v.x, v.y, v.z, v.w};
#pragma unroll
    for (int j = 0; j < 4; ++j) {
        __hip_bfloat16 h = __float2bfloat16(vf[j]);
        h4[j] = *reinterpret_cast<short*>(&h);
        __hip_bfloat16 l = __float2bfloat16(vf[j] - __bfloat162float(h));
        l4[j] = *reinterpret_cast<short*>(&l);
    }
    *(uint2*)(hi + i) = *(uint2*)h4;
    *(uint2*)(lo + i) = *(uint2*)l4;
}

// ---------------- K0b: f32 -> bf16 weight staging ----------------
__global__ __launch_bounds__(256) void k_cvt(
    const float* __restrict__ s, __hip_bfloat16* __restrict__ d, int n)
{
    const int i = (blockIdx.x * 256 + threadIdx.x) * 4;
    if (i + 3 < n) {
        const float4 v = *(const float4*)(s + i);
        d[i]     = __float2bfloat16(v.x);
        d[i + 1] = __float2bfloat16(v.y);
        d[i + 2] = __float2bfloat16(v.z);
        d[i + 3] = __float2bfloat16(v.w);
    }
}

// ---------------- K_gram2: G[b][i][j] = x_i.x_j + 1 (split-f32 MFMA) -----
__global__ __launch_bounds__(256) void k_gram2(
    const short* __restrict__ Xhi, const short* __restrict__ Xlo,
    float* __restrict__ g)
{
    const int wid = threadIdx.x >> 6, lane = threadIdx.x & 63;
    const int r16 = lane & 15, quad = lane >> 4;
    const int b = blockIdx.z;
    const int m0 = blockIdx.y * 64;
    const int n0 = blockIdx.x * 64 + wid * 16;
    const short* XH = Xhi + b * S * H;
    const short* XL = Xlo + b * S * H;

    f32x4 acc[4];
#pragma unroll
    for (int i = 0; i < 4; ++i) acc[i] = (f32x4){0, 0, 0, 0};

    for (int k0 = 0; k0 < H; k0 += 32) {
        const int k = k0 + quad * 8;
        const bf16x8 bh = *(const bf16x8*)(XH + (n0 + r16) * H + k);
        const bf16x8 bl = *(const bf16x8*)(XL + (n0 + r16) * H + k);
#pragma unroll
        for (int i = 0; i < 4; ++i) {
            const bf16x8 ah = *(const bf16x8*)(XH + (m0 + i * 16 + r16) * H + k);
            const bf16x8 al = *(const bf16x8*)(XL + (m0 + i * 16 + r16) * H + k);
            acc[i] = __builtin_amdgcn_mfma_f32_16x16x32_bf16(ah, bh, acc[i], 0, 0, 0);
            acc[i] = __builtin_amdgcn_mfma_f32_16x16x32_bf16(ah, bl, acc[i], 0, 0, 0);
            acc[i] = __builtin_amdgcn_mfma_f32_16x16x32_bf16(al, bh, acc[i], 0, 0, 0);
        }
    }
    const int col = n0 + r16;
#pragma unroll
    for (int i = 0; i < 4; ++i)
#pragma unroll
        for (int r = 0; r < 4; ++r) {
            const int row = m0 + i * 16 + quad * 4 + r;
            g[(b * S + row) * S + col] = acc[i][r] + 1.f;
        }
}

// ---------------- K_base: Base0 = X.W0^T + b0 (split-f32 MFMA) ----------
__global__ __launch_bounds__(256) void k_base(
    const short* __restrict__ Xhi, const short* __restrict__ Xlo,
    const short* __restrict__ Whi, const short* __restrict__ Wlo,
    const float* __restrict__ b0, float* __restrict__ base0)
{
    const int wid = threadIdx.x >> 6, lane = threadIdx.x & 63;
    const int r16 = lane & 15, quad = lane >> 4;
    const int m0 = blockIdx.y * 64;
    const int n0 = blockIdx.x * 64 + wid * 16;

    f32x4 acc[4];
#pragma unroll
    for (int i = 0; i < 4; ++i) acc[i] = (f32x4){0, 0, 0, 0};

    for (int k0 = 0; k0 < H; k0 += 32) {
        const int k = k0 + quad * 8;
        const bf16x8 bh = *(const bf16x8*)(Whi + (n0 + r16) * H + k);
        const bf16x8 bl = *(const bf16x8*)(Wlo + (n0 + r16) * H + k);
#pragma unroll
        for (int i = 0; i < 4; ++i) {
            const bf16x8 ah = *(const bf16x8*)(Xhi + (m0 + i * 16 + r16) * H + k);
            const bf16x8 al = *(const bf16x8*)(Xlo + (m0 + i * 16 + r16) * H + k);
            acc[i] = __builtin_amdgcn_mfma_f32_16x16x32_bf16(ah, bh, acc[i], 0, 0, 0);
            acc[i] = __builtin_amdgcn_mfma_f32_16x16x32_bf16(ah, bl, acc[i], 0, 0, 0);
            acc[i] = __builtin_amdgcn_mfma_f32_16x16x32_bf16(al, bh, acc[i], 0, 0, 0);
        }
    }
    const int col = n0 + r16;
    const float bv = b0[col];
#pragma unroll
    for (int i = 0; i < 4; ++i)
#pragma unroll
        for (int r = 0; r < 4; ++r) {
            const int row = m0 + i * 16 + quad * 4 + r;
            base0[row * H + col] = acc[i][r] + bv;
        }
}

// ---------------- K_recur3: triangular solve (I + LR*A) D = Base0 - Xn ---
// pred = D + Xn. Grid 96 wgs: (b, 16-h window). Wave w: 4 h's, lane = t_local.
__global__ __launch_bounds__(256) void k_recur3(
    const float* __restrict__ x,
    const float* __restrict__ base0,
    const float* __restrict__ g,
    float* __restrict__ pred_f,
    __hip_bfloat16* __restrict__ pred_h)
{
    __shared__ float tB[64 * 17];
    __shared__ float tX[64 * 17];
    __shared__ float Dl[256 * 17];
    const int tid = threadIdx.x;
    const int w = tid >> 6, lane = tid & 63;
    const int b = blockIdx.x / 48, hb = blockIdx.x % 48;
    const int h0 = hb * 16;
    const int ho = w * 4;
    const int ct = tid >> 2;          // cooperative row 0..63
    const int cq = (tid & 3) * 4;     // cooperative col {0,4,8,12}

    for (int c = 0; c < NC; ++c) {
        const int t0 = c * C;
        __syncthreads();
        {   // stage tB = Base0 - Xn, tX = Xn (transposed into LDS)
            const int gm = b * S + t0 + ct;
            const float4 bv = *(const float4*)(base0 + gm * H + h0 + cq);
            float4 xv = {0.f, 0.f, 0.f, 0.f};
            if (t0 + ct + 1 < S)
                xv = *(const float4*)(x + (gm + 1) * H + h0 + cq);
            tB[ct * 17 + cq + 0] = bv.x - xv.x;
            tB[ct * 17 + cq + 1] = bv.y - xv.y;
            tB[ct * 17 + cq + 2] = bv.z - xv.z;
            tB[ct * 17 + cq + 3] = bv.w - xv.w;
            tX[ct * 17 + cq + 0] = xv.x;
            tX[ct * 17 + cq + 1] = xv.y;
            tX[ct * 17 + cq + 2] = xv.z;
            tX[ct * 17 + cq + 3] = xv.w;
        }
        __syncthreads();
        float R[4], Xn[4];
#pragma unroll
        for (int h = 0; h < 4; ++h) {
            R[h]  = tB[lane * 17 + ho + h];
            Xn[h] = tX[lane * 17 + ho + h];
        }
        // cross-chunk corrections: R[t] -= LR * G[cs, t] * D[cs]
        const float* gcol = g + (long)(b * S) * S + t0 + lane;
        for (int cs = 0; cs < t0; ++cs) {
            const float Gv = gcol[(long)cs * S];
            const float* dr = &Dl[cs * 17 + ho];
            R[0] -= LRC * Gv * dr[0];
            R[1] -= LRC * Gv * dr[1];
            R[2] -= LRC * Gv * dr[2];
            R[3] -= LRC * Gv * dr[3];
        }
        // in-chunk forward substitution (serial over s)
        for (int s = 0; s < C; ++s) {
            float dsb[4];
#pragma unroll
            for (int h = 0; h < 4; ++h) dsb[h] = __shfl(R[h], s, 64);
            const float Gv = gcol[(long)(t0 + s) * S];
            const float mlt = (lane > s) ? LRC : 0.f;
#pragma unroll
            for (int h = 0; h < 4; ++h) R[h] -= mlt * Gv * dsb[h];
        }
        // persist D (wave-private h-window; read by same wave in later chunks)
#pragma unroll
        for (int h = 0; h < 4; ++h) Dl[(t0 + lane) * 17 + ho + h] = R[h];
        // P = D + Xn -> transpose back through tB, store
        __syncthreads();
#pragma unroll
        for (int h = 0; h < 4; ++h) tB[lane * 17 + ho + h] = R[h] + Xn[h];
        __syncthreads();
        {
            const int gm = b * S + t0 + ct;
            float4 pv;
            pv.x = tB[ct * 17 + cq + 0];
            pv.y = tB[ct * 17 + cq + 1];
            pv.z = tB[ct * 17 + cq + 2];
            pv.w = tB[ct * 17 + cq + 3];
            *(float4*)(pred_f + gm * H + h0 + cq) = pv;
            short p4[4];
            p4[0] = bfbits(pv.x); p4[1] = bfbits(pv.y);
            p4[2] = bfbits(pv.z); p4[3] = bfbits(pv.w);
            *(uint2*)((short*)pred_h + gm * H + h0 + cq) = *(uint2*)p4;
        }
    }
}

// ---------------- B-fragment loaders ----------------
__device__ inline bf16x8 ldb16(const void* p, long off) {
    return *(const bf16x8*)((const short*)p + off);
}
__device__ inline bf16x8 ldb32(const void* p, long off) {
    const float* f = (const float*)p + off;
    const float4 a = *(const float4*)f;
    const float4 b = *(const float4*)(f + 4);
    bf16x8 r;
    r[0] = bfbits(a.x); r[1] = bfbits(a.y); r[2] = bfbits(a.z); r[3] = bfbits(a.w);
    r[4] = bfbits(b.x); r[5] = bfbits(b.y); r[6] = bfbits(b.z); r[7] = bfbits(b.w);
    return r;
}

// ---------------- K2: gate/up GEMMs + sigmoid*up, 64m x 16n per wave ------
template<bool WB>
__global__ __launch_bounds__(256) void k_gateup2(
    const __hip_bfloat16* __restrict__ predh,
    const void* __restrict__ gw, const float* __restrict__ gb,
    const void* __restrict__ uw, const float* __restrict__ ub,
    __hip_bfloat16* __restrict__ hid)
{
    const int wid = threadIdx.x >> 6, lane = threadIdx.x & 63;
    const int r16 = lane & 15, quad = lane >> 4;
    const int m0 = blockIdx.y * 64;
    const int n0 = blockIdx.x * 64 + wid * 16;

    f32x4 ag[4], au[4];
#pragma unroll
    for (int i = 0; i < 4; ++i) { ag[i] = (f32x4){0,0,0,0}; au[i] = (f32x4){0,0,0,0}; }
    const short* A = (const short*)predh;
    const long brow = (long)(n0 + r16) * H;

    for (int k0 = 0; k0 < H; k0 += 32) {
        const int k = k0 + quad * 8;
        const bf16x8 bg = WB ? ldb16(gw, brow + k) : ldb32(gw, brow + k);
        const bf16x8 bu = WB ? ldb16(uw, brow + k) : ldb32(uw, brow + k);
#pragma unroll
        for (int i = 0; i < 4; ++i) {
            const bf16x8 af = *(const bf16x8*)(A + (m0 + i * 16 + r16) * H + k);
            ag[i] = __builtin_amdgcn_mfma_f32_16x16x32_bf16(af, bg, ag[i], 0, 0, 0);
            au[i] = __builtin_amdgcn_mfma_f32_16x16x32_bf16(af, bu, au[i], 0, 0, 0);
        }
    }
    const int ocol = n0 + r16;
    const float gbv = gb[ocol], ubv = ub[ocol];
#pragma unroll
    for (int i = 0; i < 4; ++i)
#pragma unroll
        for (int r = 0; r < 4; ++r) {
            const int orow = m0 + i * 16 + quad * 4 + r;
            const float gg = ag[i][r] + gbv;
            const float u = au[i][r] + ubv;
            const float sg = 1.f / (1.f + __expf(-gg));
            hid[orow * H4 + ocol] = __float2bfloat16(sg * u);
        }
}

// ---------------- K3: down GEMM + bias + pred residual, 32m x 16n/wave ----
template<bool WB>
__global__ __launch_bounds__(256) void k_down2(
    const __hip_bfloat16* __restrict__ hid,
    const void* __restrict__ dw, const float* __restrict__ db,
    const float* __restrict__ predf, float* __restrict__ dout)
{
    const int wid = threadIdx.x >> 6, lane = threadIdx.x & 63;
    const int r16 = lane & 15, quad = lane >> 4;
    const int m0 = blockIdx.y * 32;
    const int n0 = blockIdx.x * 64 + wid * 16;

    f32x4 ac[2];
    ac[0] = (f32x4){0,0,0,0}; ac[1] = (f32x4){0,0,0,0};
    const short* A = (const short*)hid;
    const long brow = (long)(n0 + r16) * H4;

    for (int k0 = 0; k0 < H4; k0 += 32) {
        const int k = k0 + quad * 8;
        const bf16x8 bd = WB ? ldb16(dw, brow + k) : ldb32(dw, brow + k);
#pragma unroll
        for (int i = 0; i < 2; ++i) {
            const bf16x8 af = *(const bf16x8*)(A + (m0 + i * 16 + r16) * H4 + k);
            ac[i] = __builtin_amdgcn_mfma_f32_16x16x32_bf16(af, bd, ac[i], 0, 0, 0);
        }
    }
    const int ocol = n0 + r16;
    const float dbv = db[ocol];
#pragma unroll
    for (int i = 0; i < 2; ++i)
#pragma unroll
        for (int r = 0; r < 4; ++r) {
            const int orow = m0 + i * 16 + quad * 4 + r;
            dout[orow * H + ocol] = ac[i][r] + dbv + predf[orow * H + ocol];
        }
}

// ---------------- K4: row-wise LayerNorm -> f32 out ----------------
__global__ __launch_bounds__(256) void k_ln(
    const float* __restrict__ dout,
    const float* __restrict__ nw,
    const float* __restrict__ nb,
    float* __restrict__ out)
{
    const int m = blockIdx.x;
    const int tid = threadIdx.x;
    const float* rowp = dout + m * H;

    float v[3];
    float s = 0.f, s2 = 0.f;
#pragma unroll
    for (int j = 0; j < 3; ++j) {
        v[j] = rowp[tid + 256 * j];
        s += v[j];
        s2 += v[j] * v[j];
    }
#pragma unroll
    for (int off = 32; off >= 1; off >>= 1) {
        s  += __shfl_xor(s, off, 64);
        s2 += __shfl_xor(s2, off, 64);
    }
    __shared__ float rs[4], rs2[4];
    const int wid = tid >> 6, lane = tid & 63;
    if (lane == 0) { rs[wid] = s; rs2[wid] = s2; }
    __syncthreads();
    s  = rs[0] + rs[1] + rs[2] + rs[3];
    s2 = rs2[0] + rs2[1] + rs2[2] + rs2[3];
    const float mu  = s / (float)H;
    const float var = s2 / (float)H - mu * mu;
    const float inv = rsqrtf(var + 1e-5f);
#pragma unroll
    for (int j = 0; j < 3; ++j) {
        const int hh = tid + 256 * j;
        out[m * H + hh] = (v[j] - mu) * inv * nw[hh] + nb[hh];
    }
}

// ---------------- launch ----------------
extern "C" void kernel_launch(void* const* d_in, const int* in_sizes, int n_in,
                              void* d_out, int out_size, void* d_ws, size_t ws_size,
                              hipStream_t stream)
{
    const float* x   = (const float*)d_in[0];
    const float* W0  = (const float*)d_in[1];
    const float* b0  = (const float*)d_in[2];
    const float* gw  = (const float*)d_in[3];
    const float* gb  = (const float*)d_in[4];
    const float* uw  = (const float*)d_in[5];
    const float* ub  = (const float*)d_in[6];
    const float* dw  = (const float*)d_in[7];
    const float* db  = (const float*)d_in[8];
    const float* nw  = (const float*)d_in[9];
    const float* nb  = (const float*)d_in[10];

    char* ws = (char*)d_ws;
    float*          pred_f = (float*)(ws);                       // 1,572,864
    __hip_bfloat16* pred_h = (__hip_bfloat16*)(ws + 1572864);    //   786,432
    __hip_bfloat16* hid    = (__hip_bfloat16*)(ws + 2359296);    // 3,145,728
    float*          base0  = (float*)(ws + 5505024);             // 1,572,864
    float*          dout_f = (float*)(ws + 5505024);             // alias: base0 dead before k_down2
    float*          g      = (float*)(ws + 7077888);             //   524,288
    short*          Xhi    = (short*)(ws + 7602176);             //   786,432
    short*          Xlo    = (short*)(ws + 8388608);             //   786,432
    short*          Whi    = (short*)(ws + 9175040);             // 1,179,648
    short*          Wlo    = (short*)(ws + 10354688);            // 1,179,648
    // core end: 11,534,336
    const size_t WNEED = 11534336ULL + 3ULL * 4718592ULL;        // + bf16 MLP weights
    const bool wb = ws_size >= WNEED;
    __hip_bfloat16* gw2 = (__hip_bfloat16*)(ws + 11534336);
    __hip_bfloat16* uw2 = (__hip_bfloat16*)(ws + 11534336 + 4718592);
    __hip_bfloat16* dw2 = (__hip_bfloat16*)(ws + 11534336 + 2 * 4718592);
    const int WN = H * H4;

    const int NX = M * H;        // 393216
    const int NW = H * H;        // 589824
    k_split<<<dim3(NX / 1024), 256, 0, stream>>>(x, Xhi, Xlo, NX);
    k_split<<<dim3(NW / 1024), 256, 0, stream>>>(W0, Whi, Wlo, NW);
    if (wb) {
        k_cvt<<<dim3(WN / 1024), 256, 0, stream>>>(gw, gw2, WN);
        k_cvt<<<dim3(WN / 1024), 256, 0, stream>>>(uw, uw2, WN);
        k_cvt<<<dim3(WN / 1024), 256, 0, stream>>>(dw, dw2, WN);
    }
    k_gram2<<<dim3(4, 4, BB), 256, 0, stream>>>(Xhi, Xlo, g);
    k_base<<<dim3(12, 8), 256, 0, stream>>>(Xhi, Xlo, Whi, Wlo, b0, base0);
    k_recur3<<<dim3(96), 256, 0, stream>>>(x, base0, g, pred_f, pred_h);
    if (wb) {
        k_gateup2<true><<<dim3(H4 / 64, M / 64), 256, 0, stream>>>(pred_h, gw2, gb, uw2, ub, hid);
        k_down2<true><<<dim3(H / 64, M / 32), 256, 0, stream>>>(hid, dw2, db, pred_f, dout_f);
    } else {
        k_gateup2<false><<<dim3(H4 / 64, M / 64), 256, 0, stream>>>(pred_h, gw, gb, uw, ub, hid);
        k_down2<false><<<dim3(H / 64, M / 32), 256, 0, stream>>>(hid, dw, db, pred_f, dout_f);
    }
    k_ln<<<dim3(M), 256, 0, stream>>>(dout_f, nw, nb, (float*)d_out);
}

// Round 5
// 227.325 us; speedup vs baseline: 1.8060x; 1.1780x over previous
//
#include <hip/hip_runtime.h>
#include <hip/hip_bf16.h>

#define H   768
#define H4  3072
#define S   256
#define BB  2
#define M   (BB * S)          // 512 rows of (b,t)
#define LRC 0.01f
#define C   64                // chunk size
#define NC  (S / C)           // 4 chunks

typedef __attribute__((ext_vector_type(8))) short bf16x8;
typedef __attribute__((ext_vector_type(4))) float f32x4;

__device__ inline short bfbits(float f) {
    __hip_bfloat16 h = __float2bfloat16(f);
    return *reinterpret_cast<short*>(&h);
}

// ---------------- K_stage: all input staging in ONE kernel ----------------
// groups of 4 floats. Regions (group idx, all block-aligned at 256):
//  [0,98304)        x      -> Xhi/Xlo split
//  [98304,245760)   W0     -> Whi/Wlo split
//  [245760,835584)  gw     -> gw2 cvt          (FULL only)
//  [835584,1425408) uw     -> uw2 cvt          (FULL only)
//  [1425408,2015232)dw     -> dw2 cvt          (FULL only)
__global__ __launch_bounds__(256) void k_stage(
    const float* __restrict__ x,  const float* __restrict__ W0,
    const float* __restrict__ gw, const float* __restrict__ uw,
    const float* __restrict__ dw,
    short* __restrict__ Xhi, short* __restrict__ Xlo,
    short* __restrict__ Whi, short* __restrict__ Wlo,
    short* __restrict__ gw2, short* __restrict__ uw2, short* __restrict__ dw2)
{
    const long gid = (long)blockIdx.x * 256 + threadIdx.x;
    const float* src; short* hp; short* lp = nullptr; long base;
    if (gid < 98304)        { src = x;  hp = Xhi; lp = Xlo; base = 0; }
    else if (gid < 245760)  { src = W0; hp = Whi; lp = Wlo; base = 98304; }
    else if (gid < 835584)  { src = gw; hp = gw2; base = 245760; }
    else if (gid < 1425408) { src = uw; hp = uw2; base = 835584; }
    else                    { src = dw; hp = dw2; base = 1425408; }
    const long i = (gid - base) * 4;
    const float4 v = *(const float4*)(src + i);
    const float vf[4] = {v.x, v.y, v.z, v.w};
    short h4[4], l4[4];
#pragma unroll
    for (int j = 0; j < 4; ++j) {
        h4[j] = bfbits(vf[j]);
        __hip_bfloat16 hb = *reinterpret_cast<__hip_bfloat16*>(&h4[j]);
        l4[j] = bfbits(vf[j] - __bfloat162float(hb));
    }
    *(uint2*)(hp + i) = *(uint2*)h4;
    if (lp) *(uint2*)(lp + i) = *(uint2*)l4;
}

// ---------------- K_gram_base: merged Gram + Base0 GEMMs ------------------
// blocks [0,32): G[b][i][j] = x_i.x_j + 1 ; blocks [32,128): Base0 = X.W0^T + b0
__global__ __launch_bounds__(256) void k_gram_base(
    const short* __restrict__ Xhi, const short* __restrict__ Xlo,
    const short* __restrict__ Whi, const short* __restrict__ Wlo,
    const float* __restrict__ b0,
    float* __restrict__ g, float* __restrict__ base0)
{
    const int wid = threadIdx.x >> 6, lane = threadIdx.x & 63;
    const int r16 = lane & 15, quad = lane >> 4;
    const int id = blockIdx.x;

    f32x4 acc[4];
#pragma unroll
    for (int i = 0; i < 4; ++i) acc[i] = (f32x4){0, 0, 0, 0};

    if (id < 32) {  // ---- gram ----
        const int bx = id & 3, by = (id >> 2) & 3, b = id >> 4;
        const int m0 = by * 64, n0 = bx * 64 + wid * 16;
        const short* XH = Xhi + b * S * H;
        const short* XL = Xlo + b * S * H;
        for (int k0 = 0; k0 < H; k0 += 32) {
            const int k = k0 + quad * 8;
            const bf16x8 bh = *(const bf16x8*)(XH + (n0 + r16) * H + k);
            const bf16x8 bl = *(const bf16x8*)(XL + (n0 + r16) * H + k);
#pragma unroll
            for (int i = 0; i < 4; ++i) {
                const bf16x8 ah = *(const bf16x8*)(XH + (m0 + i * 16 + r16) * H + k);
                const bf16x8 al = *(const bf16x8*)(XL + (m0 + i * 16 + r16) * H + k);
                acc[i] = __builtin_amdgcn_mfma_f32_16x16x32_bf16(ah, bh, acc[i], 0, 0, 0);
                acc[i] = __builtin_amdgcn_mfma_f32_16x16x32_bf16(ah, bl, acc[i], 0, 0, 0);
                acc[i] = __builtin_amdgcn_mfma_f32_16x16x32_bf16(al, bh, acc[i], 0, 0, 0);
            }
        }
        const int col = n0 + r16;
#pragma unroll
        for (int i = 0; i < 4; ++i)
#pragma unroll
            for (int r = 0; r < 4; ++r) {
                const int row = m0 + i * 16 + quad * 4 + r;
                g[(b * S + row) * S + col] = acc[i][r] + 1.f;
            }
    } else {        // ---- base ----
        const int id2 = id - 32;
        const int m0 = (id2 / 12) * 64, n0 = (id2 % 12) * 64 + wid * 16;
        for (int k0 = 0; k0 < H; k0 += 32) {
            const int k = k0 + quad * 8;
            const bf16x8 bh = *(const bf16x8*)(Whi + (n0 + r16) * H + k);
            const bf16x8 bl = *(const bf16x8*)(Wlo + (n0 + r16) * H + k);
#pragma unroll
            for (int i = 0; i < 4; ++i) {
                const bf16x8 ah = *(const bf16x8*)(Xhi + (m0 + i * 16 + r16) * H + k);
                const bf16x8 al = *(const bf16x8*)(Xlo + (m0 + i * 16 + r16) * H + k);
                acc[i] = __builtin_amdgcn_mfma_f32_16x16x32_bf16(ah, bh, acc[i], 0, 0, 0);
                acc[i] = __builtin_amdgcn_mfma_f32_16x16x32_bf16(ah, bl, acc[i], 0, 0, 0);
                acc[i] = __builtin_amdgcn_mfma_f32_16x16x32_bf16(al, bh, acc[i], 0, 0, 0);
            }
        }
        const int col = n0 + r16;
        const float bv = b0[col];
#pragma unroll
        for (int i = 0; i < 4; ++i)
#pragma unroll
            for (int r = 0; r < 4; ++r) {
                const int row = m0 + i * 16 + quad * 4 + r;
                base0[row * H + col] = acc[i][r] + bv;
            }
    }
}

// ---------------- K_recur3: triangular solve (I + LR*A) D = Base0 - Xn ---
__global__ __launch_bounds__(256) void k_recur3(
    const float* __restrict__ x,
    const float* __restrict__ base0,
    const float* __restrict__ g,
    float* __restrict__ pred_f,
    __hip_bfloat16* __restrict__ pred_h)
{
    __shared__ float tB[64 * 17];
    __shared__ float tX[64 * 17];
    __shared__ float Dl[256 * 17];
    __shared__ float Gs[64 * 65];        // in-chunk 64x64 G block (pad 65)
    const int tid = threadIdx.x;
    const int w = tid >> 6, lane = tid & 63;
    const int b = blockIdx.x / 48, hb = blockIdx.x % 48;
    const int h0 = hb * 16;
    const int ho = w * 4;
    const int ct = tid >> 2;
    const int cq = (tid & 3) * 4;

    for (int c = 0; c < NC; ++c) {
        const int t0 = c * C;
        __syncthreads();
        {   // stage tB = Base0 - Xn, tX = Xn, Gs = G[t0+s][t0+t]
            const int gm = b * S + t0 + ct;
            const float4 bv = *(const float4*)(base0 + gm * H + h0 + cq);
            float4 xv = {0.f, 0.f, 0.f, 0.f};
            if (t0 + ct + 1 < S)
                xv = *(const float4*)(x + (gm + 1) * H + h0 + cq);
            tB[ct * 17 + cq + 0] = bv.x - xv.x;
            tB[ct * 17 + cq + 1] = bv.y - xv.y;
            tB[ct * 17 + cq + 2] = bv.z - xv.z;
            tB[ct * 17 + cq + 3] = bv.w - xv.w;
            tX[ct * 17 + cq + 0] = xv.x;
            tX[ct * 17 + cq + 1] = xv.y;
            tX[ct * 17 + cq + 2] = xv.z;
            tX[ct * 17 + cq + 3] = xv.w;
#pragma unroll
            for (int j = 0; j < 16; ++j) {
                const int idx = tid + 256 * j;
                const int row = idx >> 6, col = idx & 63;
                Gs[row * 65 + col] = g[(long)(b * S + t0 + row) * S + t0 + col];
            }
        }
        __syncthreads();
        float R[4], Xn[4];
#pragma unroll
        for (int h = 0; h < 4; ++h) {
            R[h]  = tB[lane * 17 + ho + h];
            Xn[h] = tX[lane * 17 + ho + h];
        }
        // cross-chunk corrections: R[t] -= LR * G[cs, t0+t] * D[cs]
        const float* gcol = g + (long)(b * S) * S + t0 + lane;
#pragma unroll 4
        for (int cs = 0; cs < t0; ++cs) {
            const float Gv = gcol[(long)cs * S];
            const float* dr = &Dl[cs * 17 + ho];
            R[0] -= LRC * Gv * dr[0];
            R[1] -= LRC * Gv * dr[1];
            R[2] -= LRC * Gv * dr[2];
            R[3] -= LRC * Gv * dr[3];
        }
        // in-chunk forward substitution (serial over s) — G from LDS
        for (int s = 0; s < C; ++s) {
            float dsb[4];
#pragma unroll
            for (int h = 0; h < 4; ++h) dsb[h] = __shfl(R[h], s, 64);
            const float Gv = Gs[s * 65 + lane];
            const float mlt = (lane > s) ? LRC : 0.f;
#pragma unroll
            for (int h = 0; h < 4; ++h) R[h] -= mlt * Gv * dsb[h];
        }
#pragma unroll
        for (int h = 0; h < 4; ++h) Dl[(t0 + lane) * 17 + ho + h] = R[h];
        __syncthreads();
#pragma unroll
        for (int h = 0; h < 4; ++h) tB[lane * 17 + ho + h] = R[h] + Xn[h];
        __syncthreads();
        {
            const int gm = b * S + t0 + ct;
            float4 pv;
            pv.x = tB[ct * 17 + cq + 0];
            pv.y = tB[ct * 17 + cq + 1];
            pv.z = tB[ct * 17 + cq + 2];
            pv.w = tB[ct * 17 + cq + 3];
            *(float4*)(pred_f + gm * H + h0 + cq) = pv;
            short p4[4];
            p4[0] = bfbits(pv.x); p4[1] = bfbits(pv.y);
            p4[2] = bfbits(pv.z); p4[3] = bfbits(pv.w);
            *(uint2*)((short*)pred_h + gm * H + h0 + cq) = *(uint2*)p4;
        }
    }
}

// ---------------- K_gateup3: LDS-tiled fused gate+up GEMM ----------------
// 64m x 128n x 32k tile per wg (256 thr). Wave (wm,wn): 32m x 64n, 2x4 frags
// per matrix. LDS rows padded to 40 shorts (80B): conflict-free ds_read_b128.
#define RS 40
__global__ __launch_bounds__(256) void k_gateup3(
    const __hip_bfloat16* __restrict__ predh,
    const short* __restrict__ gwp, const float* __restrict__ gb,
    const short* __restrict__ uwp, const float* __restrict__ ub,
    __hip_bfloat16* __restrict__ hid)
{
    __shared__ int4 smv[1600];           // 25600 B
    short* sm = (short*)smv;
    short* sA = sm;                      // 64  x RS
    short* sG = sm + 64 * RS;            // 128 x RS
    short* sU = sm + (64 + 128) * RS;    // 128 x RS

    const int tid = threadIdx.x;
    const int wid = tid >> 6, lane = tid & 63;
    const int r16 = lane & 15, quad = lane >> 4;
    const int wm = wid & 1, wn = wid >> 1;
    const int n0 = blockIdx.x * 128;
    const int m0 = blockIdx.y * 64;

    const int srow = tid >> 2;           // 0..63 staging row
    const int sch  = (tid & 3) * 8;      // k-chunk offset (elements)
    const short* A = (const short*)predh;

    f32x4 ag[2][4], au[2][4];
#pragma unroll
    for (int i = 0; i < 2; ++i)
#pragma unroll
        for (int j = 0; j < 4; ++j) { ag[i][j] = (f32x4){0,0,0,0}; au[i][j] = (f32x4){0,0,0,0}; }

    int4 rA, rG0, rG1, rU0, rU1;
    {
        const int k = sch;
        rA  = *(const int4*)(A   + (m0 + srow) * H + k);
        rG0 = *(const int4*)(gwp + (n0 + srow) * H + k);
        rG1 = *(const int4*)(gwp + (n0 + 64 + srow) * H + k);
        rU0 = *(const int4*)(uwp + (n0 + srow) * H + k);
        rU1 = *(const int4*)(uwp + (n0 + 64 + srow) * H + k);
    }
    for (int it = 0; it < 24; ++it) {
        *(int4*)(sA + srow * RS + sch)        = rA;
        *(int4*)(sG + srow * RS + sch)        = rG0;
        *(int4*)(sG + (64 + srow) * RS + sch) = rG1;
        *(int4*)(sU + srow * RS + sch)        = rU0;
        *(int4*)(sU + (64 + srow) * RS + sch) = rU1;
        __syncthreads();
        if (it < 23) {
            const int k = (it + 1) * 32 + sch;
            rA  = *(const int4*)(A   + (m0 + srow) * H + k);
            rG0 = *(const int4*)(gwp + (n0 + srow) * H + k);
            rG1 = *(const int4*)(gwp + (n0 + 64 + srow) * H + k);
            rU0 = *(const int4*)(uwp + (n0 + srow) * H + k);
            rU1 = *(const int4*)(uwp + (n0 + 64 + srow) * H + k);
        }
        bf16x8 aF[2], gF[4], uF[4];
#pragma unroll
        for (int i = 0; i < 2; ++i)
            aF[i] = *(const bf16x8*)(sA + (wm * 32 + i * 16 + r16) * RS + quad * 8);
#pragma unroll
        for (int j = 0; j < 4; ++j) {
            gF[j] = *(const bf16x8*)(sG + (wn * 64 + j * 16 + r16) * RS + quad * 8);
            uF[j] = *(const bf16x8*)(sU + (wn * 64 + j * 16 + r16) * RS + quad * 8);
        }
#pragma unroll
        for (int i = 0; i < 2; ++i)
#pragma unroll
            for (int j = 0; j < 4; ++j) {
                ag[i][j] = __builtin_amdgcn_mfma_f32_16x16x32_bf16(aF[i], gF[j], ag[i][j], 0, 0, 0);
                au[i][j] = __builtin_amdgcn_mfma_f32_16x16x32_bf16(aF[i], uF[j], au[i][j], 0, 0, 0);
            }
        __syncthreads();
    }
#pragma unroll
    for (int j = 0; j < 4; ++j) {
        const int ocol = n0 + wn * 64 + j * 16 + r16;
        const float gbv = gb[ocol], ubv = ub[ocol];
#pragma unroll
        for (int i = 0; i < 2; ++i)
#pragma unroll
            for (int r = 0; r < 4; ++r) {
                const int orow = m0 + wm * 32 + i * 16 + quad * 4 + r;
                const float gg = ag[i][j][r] + gbv;
                const float u  = au[i][j][r] + ubv;
                const float sg = 1.f / (1.f + __expf(-gg));
                hid[orow * H4 + ocol] = __float2bfloat16(sg * u);
            }
    }
}

// ---------------- old direct gate/up (fallback when ws too small) --------
__device__ inline bf16x8 ldb32(const void* p, long off) {
    const float* f = (const float*)p + off;
    const float4 a = *(const float4*)f;
    const float4 b = *(const float4*)(f + 4);
    bf16x8 r;
    r[0] = bfbits(a.x); r[1] = bfbits(a.y); r[2] = bfbits(a.z); r[3] = bfbits(a.w);
    r[4] = bfbits(b.x); r[5] = bfbits(b.y); r[6] = bfbits(b.z); r[7] = bfbits(b.w);
    return r;
}
__device__ inline bf16x8 ldb16(const void* p, long off) {
    return *(const bf16x8*)((const short*)p + off);
}

template<bool WB>
__global__ __launch_bounds__(256) void k_gateup2(
    const __hip_bfloat16* __restrict__ predh,
    const void* __restrict__ gw, const float* __restrict__ gb,
    const void* __restrict__ uw, const float* __restrict__ ub,
    __hip_bfloat16* __restrict__ hid)
{
    const int wid = threadIdx.x >> 6, lane = threadIdx.x & 63;
    const int r16 = lane & 15, quad = lane >> 4;
    const int m0 = blockIdx.y * 64;
    const int n0 = blockIdx.x * 64 + wid * 16;

    f32x4 ag[4], au[4];
#pragma unroll
    for (int i = 0; i < 4; ++i) { ag[i] = (f32x4){0,0,0,0}; au[i] = (f32x4){0,0,0,0}; }
    const short* A = (const short*)predh;
    const long brow = (long)(n0 + r16) * H;

    for (int k0 = 0; k0 < H; k0 += 32) {
        const int k = k0 + quad * 8;
        const bf16x8 bg = WB ? ldb16(gw, brow + k) : ldb32(gw, brow + k);
        const bf16x8 bu = WB ? ldb16(uw, brow + k) : ldb32(uw, brow + k);
#pragma unroll
        for (int i = 0; i < 4; ++i) {
            const bf16x8 af = *(const bf16x8*)(A + (m0 + i * 16 + r16) * H + k);
            ag[i] = __builtin_amdgcn_mfma_f32_16x16x32_bf16(af, bg, ag[i], 0, 0, 0);
            au[i] = __builtin_amdgcn_mfma_f32_16x16x32_bf16(af, bu, au[i], 0, 0, 0);
        }
    }
    const int ocol = n0 + r16;
    const float gbv = gb[ocol], ubv = ub[ocol];
#pragma unroll
    for (int i = 0; i < 4; ++i)
#pragma unroll
        for (int r = 0; r < 4; ++r) {
            const int orow = m0 + i * 16 + quad * 4 + r;
            const float gg = ag[i][r] + gbv;
            const float u = au[i][r] + ubv;
            const float sg = 1.f / (1.f + __expf(-gg));
            hid[orow * H4 + ocol] = __float2bfloat16(sg * u);
        }
}

// ---------------- K_down2: down GEMM + bias + pred residual --------------
template<bool WB>
__global__ __launch_bounds__(256) void k_down2(
    const __hip_bfloat16* __restrict__ hid,
    const void* __restrict__ dw, const float* __restrict__ db,
    const float* __restrict__ predf, float* __restrict__ dout)
{
    const int wid = threadIdx.x >> 6, lane = threadIdx.x & 63;
    const int r16 = lane & 15, quad = lane >> 4;
    const int m0 = blockIdx.y * 32;
    const int n0 = blockIdx.x * 64 + wid * 16;

    f32x4 ac[2];
    ac[0] = (f32x4){0,0,0,0}; ac[1] = (f32x4){0,0,0,0};
    const short* A = (const short*)hid;
    const long brow = (long)(n0 + r16) * H4;

    for (int k0 = 0; k0 < H4; k0 += 32) {
        const int k = k0 + quad * 8;
        const bf16x8 bd = WB ? ldb16(dw, brow + k) : ldb32(dw, brow + k);
#pragma unroll
        for (int i = 0; i < 2; ++i) {
            const bf16x8 af = *(const bf16x8*)(A + (m0 + i * 16 + r16) * H4 + k);
            ac[i] = __builtin_amdgcn_mfma_f32_16x16x32_bf16(af, bd, ac[i], 0, 0, 0);
        }
    }
    const int ocol = n0 + r16;
    const float dbv = db[ocol];
#pragma unroll
    for (int i = 0; i < 2; ++i)
#pragma unroll
        for (int r = 0; r < 4; ++r) {
            const int orow = m0 + i * 16 + quad * 4 + r;
            dout[orow * H + ocol] = ac[i][r] + dbv + predf[orow * H + ocol];
        }
}

// ---------------- K_ln: row-wise LayerNorm -> f32 out ----------------
__global__ __launch_bounds__(256) void k_ln(
    const float* __restrict__ dout,
    const float* __restrict__ nw,
    const float* __restrict__ nb,
    float* __restrict__ out)
{
    const int m = blockIdx.x;
    const int tid = threadIdx.x;
    const float* rowp = dout + m * H;

    float v[3];
    float s = 0.f, s2 = 0.f;
#pragma unroll
    for (int j = 0; j < 3; ++j) {
        v[j] = rowp[tid + 256 * j];
        s += v[j];
        s2 += v[j] * v[j];
    }
#pragma unroll
    for (int off = 32; off >= 1; off >>= 1) {
        s  += __shfl_xor(s, off, 64);
        s2 += __shfl_xor(s2, off, 64);
    }
    __shared__ float rs[4], rs2[4];
    const int wid = tid >> 6, lane = tid & 63;
    if (lane == 0) { rs[wid] = s; rs2[wid] = s2; }
    __syncthreads();
    s  = rs[0] + rs[1] + rs[2] + rs[3];
    s2 = rs2[0] + rs2[1] + rs2[2] + rs2[3];
    const float mu  = s / (float)H;
    const float var = s2 / (float)H - mu * mu;
    const float inv = rsqrtf(var + 1e-5f);
#pragma unroll
    for (int j = 0; j < 3; ++j) {
        const int hh = tid + 256 * j;
        out[m * H + hh] = (v[j] - mu) * inv * nw[hh] + nb[hh];
    }
}

// ---------------- launch ----------------
extern "C" void kernel_launch(void* const* d_in, const int* in_sizes, int n_in,
                              void* d_out, int out_size, void* d_ws, size_t ws_size,
                              hipStream_t stream)
{
    const float* x   = (const float*)d_in[0];
    const float* W0  = (const float*)d_in[1];
    const float* b0  = (const float*)d_in[2];
    const float* gw  = (const float*)d_in[3];
    const float* gb  = (const float*)d_in[4];
    const float* uw  = (const float*)d_in[5];
    const float* ub  = (const float*)d_in[6];
    const float* dw  = (const float*)d_in[7];
    const float* db  = (const float*)d_in[8];
    const float* nw  = (const float*)d_in[9];
    const float* nb  = (const float*)d_in[10];

    char* ws = (char*)d_ws;
    float*          pred_f = (float*)(ws);                       // 1,572,864
    __hip_bfloat16* pred_h = (__hip_bfloat16*)(ws + 1572864);    //   786,432
    __hip_bfloat16* hid    = (__hip_bfloat16*)(ws + 2359296);    // 3,145,728
    float*          base0  = (float*)(ws + 5505024);             // 1,572,864
    float*          dout_f = (float*)(ws + 5505024);             // alias: base0 dead before k_down2
    float*          g      = (float*)(ws + 7077888);             //   524,288
    short*          Xhi    = (short*)(ws + 7602176);             //   786,432
    short*          Xlo    = (short*)(ws + 8388608);             //   786,432
    short*          Whi    = (short*)(ws + 9175040);             // 1,179,648
    short*          Wlo    = (short*)(ws + 10354688);            // 1,179,648
    const size_t WNEED = 11534336ULL + 3ULL * 4718592ULL;
    const bool wb = ws_size >= WNEED;
    short* gw2 = (short*)(ws + 11534336);
    short* uw2 = (short*)(ws + 11534336 + 4718592);
    short* dw2 = (short*)(ws + 11534336 + 2 * 4718592);

    // staging: full (incl. MLP weight cvt) or reduced (splits only)
    const int ngroups = wb ? 2015232 : 245760;
    k_stage<<<dim3(ngroups / 256), 256, 0, stream>>>(
        x, W0, gw, uw, dw, Xhi, Xlo, Whi, Wlo, gw2, uw2, dw2);
    k_gram_base<<<dim3(128), 256, 0, stream>>>(Xhi, Xlo, Whi, Wlo, b0, g, base0);
    k_recur3<<<dim3(96), 256, 0, stream>>>(x, base0, g, pred_f, pred_h);
    if (wb) {
        k_gateup3<<<dim3(H4 / 128, M / 64), 256, 0, stream>>>(pred_h, gw2, gb, uw2, ub, hid);
        k_down2<true><<<dim3(H / 64, M / 32), 256, 0, stream>>>(hid, dw2, db, pred_f, dout_f);
    } else {
        k_gateup2<false><<<dim3(H4 / 64, M / 64), 256, 0, stream>>>(pred_h, gw, gb, uw, ub, hid);
        k_down2<false><<<dim3(H / 64, M / 32), 256, 0, stream>>>(hid, dw, db, pred_f, dout_f);
    }
    k_ln<<<dim3(M), 256, 0, stream>>>(dout_f, nw, nb, (float*)d_out);
}